// Round 1
// baseline (1221.240 us; speedup 1.0000x reference)
//
#include <hip/hip_runtime.h>

#define MAXL 20
#define NK 441  // (MAXL+1)^2

// ---------- compile-time normalization table ----------
constexpr double csqrt(double x) {
  if (x <= 0.0) return 0.0;
  double v = x, s = 1.0;
  while (v < 0.25) { v *= 4.0; s *= 0.5; }
  while (v >= 4.0) { v *= 0.25; s *= 2.0; }
  double g = v;
  for (int i = 0; i < 32; ++i) g = 0.5 * (g + v / g);
  return g * s;
}

struct NormTab { float v[MAXL + 1][MAXL + 1]; };

constexpr NormTab make_norms() {
  NormTab t{};
  const double PI = 3.14159265358979323846;
  for (int l = 0; l <= MAXL; ++l)
    for (int m = 0; m <= l; ++m) {
      double val = (2.0 * l + 1.0) / (4.0 * PI);
      for (int k = l - m + 1; k <= l + m; ++k) val /= (double)k;
      t.v[l][m] = (float)csqrt(val);
    }
  return t;
}

__device__ constexpr NormTab NORMS = make_norms();
__device__ constexpr float SQRT2F = (float)csqrt(2.0);

// ---------- kernel ----------
// One thread = one point. Legendre + Chebyshev recurrences fully unrolled
// (all array indices compile-time -> registers). Per-l output chunk
// (indices l^2 .. l^2+2l are CONTIGUOUS in the 441-wide row) is staged in
// LDS for all 256 points, then written cooperatively so lanes cover
// consecutive global addresses (row stride 1764B kills direct coalescing).
__global__ __launch_bounds__(256) void sh_kernel(
    const float* __restrict__ coords, float* __restrict__ out, int n) {
  __shared__ float buf[256][41];  // stride 41 floats (odd) -> conflict-free
  const int tid  = threadIdx.x;
  const int gid0 = blockIdx.x * 256;
  const int pid  = gid0 + tid;
  const int cid  = pid < n ? pid : n - 1;  // clamp; stores are masked below

  float x = coords[cid * 3 + 0];
  float y = coords[cid * 3 + 1];
  float z = coords[cid * 3 + 2];

  float r  = sqrtf(x * x + y * y + z * z);
  float ct = z / r;
  ct = fminf(1.0f, fmaxf(-1.0f, ct));
  float st = sqrtf(fmaxf(1.0f - ct * ct, 0.0f));

  // cos/sin of azimuth without atan2: c1=cos(theta), s1=sin(theta)
  float rxy = sqrtf(x * x + y * y);
  float c1, s1;
  if (rxy > 0.0f) { float inv = 1.0f / rxy; c1 = x * inv; s1 = y * inv; }
  else            { c1 = 1.0f; s1 = 0.0f; }  // atan2(0,0)=0

  float Pm1[MAXL + 1];  // after the l-update: P(l, m)
  float Pm2[MAXL + 1];  // P(l-1, m)
  float cm[MAXL + 1], sm[MAXL + 1];  // cos(m*theta), sin(m*theta)
  cm[0] = 1.0f; sm[0] = 0.0f;

  #pragma unroll
  for (int l = 0; l <= MAXL; ++l) {
    if (l == 0) {
      Pm1[0] = 1.0f;
    } else {
      cm[l] = cm[l - 1] * c1 - sm[l - 1] * s1;
      sm[l] = sm[l - 1] * c1 + cm[l - 1] * s1;
      const float A = (float)(2 * l - 1);
      #pragma unroll
      for (int m = 0; m <= l - 2; ++m) {
        // P(l,m) = ((2l-1) ct P(l-1,m) - (l+m-1) P(l-2,m)) / (l-m)
        float nv = (A * ct * Pm1[m] - (float)(l + m - 1) * Pm2[m])
                   * (1.0f / (float)(l - m));
        Pm2[m] = Pm1[m];
        Pm1[m] = nv;
      }
      float d = Pm1[l - 1];        // P(l-1, l-1)
      Pm2[l - 1] = d;
      Pm1[l - 1] = A * ct * d;     // P(l, l-1) = (2l-1) ct P(l-1,l-1)
      Pm1[l]     = -A * st * d;    // P(l, l)   = -(2l-1) st P(l-1,l-1)
    }

    // stage this l's 2l+1 outputs: row-chunk j=0..2l maps to flat l^2+j
    buf[tid][l] = NORMS.v[l][0] * Pm1[0];            // m = 0
    #pragma unroll
    for (int m = 1; m <= l; ++m) {
      float base = SQRT2F * (NORMS.v[l][m] * Pm1[m]);
      buf[tid][l + m] = base * cm[m];                // m > 0
      buf[tid][l - m] = base * sm[m];                // m < 0
    }
    __syncthreads();

    // cooperative, element-contiguous write of 256*(2l+1) staged values
    const int c = 2 * l + 1;
    const int colbase = l * l;
    #pragma unroll
    for (int k = 0; k < c; ++k) {
      int e = tid + k * 256;   // flat element in [0, 256*c)
      int p = e / c;           // compile-time divisor -> magic multiply
      int j = e - p * c;
      int pt = gid0 + p;
      if (pt < n) out[pt * NK + colbase + j] = buf[p][j];
    }
    __syncthreads();
  }
}

extern "C" void kernel_launch(void* const* d_in, const int* in_sizes, int n_in,
                              void* d_out, int out_size, void* d_ws, size_t ws_size,
                              hipStream_t stream) {
  const float* coords = (const float*)d_in[0];
  float* out = (float*)d_out;
  const int n = in_sizes[0] / 3;      // 500000 points
  const int grid = (n + 255) / 256;
  hipLaunchKernelGGL(sh_kernel, dim3(grid), dim3(256), 0, stream,
                     coords, out, n);
}